// Round 10
// baseline (524.110 us; speedup 1.0000x reference)
//
#include <hip/hip_runtime.h>
#include <stdint.h>

#define NC 5
#define SEGS 160            // remapped: label*32 + (idx-1), idx in [1,32]
#define MT 5                // 5 M-tiles of 32
#define HW_ (512 * 512)
#define IGNORE_L 255
#define SENT 0xFF
#define KCHUNK 2048         // pixels per segsum block
#define SPX 64              // pixels per stage per wave
#define NST (KCHUNK / SPX)  // 32 stages
#define TILE (SEGS * 128)

typedef __attribute__((ext_vector_type(8))) short short8v;
typedef __attribute__((ext_vector_type(16))) float f32x16;
typedef __attribute__((ext_vector_type(2))) unsigned short u16x2;
typedef __attribute__((ext_vector_type(2))) float float2v;
typedef __attribute__((ext_vector_type(2))) __bf16 bf16x2;

// ---------------- Pass 1: remapped seg ids + counts ----------------
__global__ __launch_bounds__(256) void seg_count_kernel(
    const int* __restrict__ labels, const int* __restrict__ indexes,
    uint8_t* __restrict__ seg, unsigned* __restrict__ counts,
    int pix_per_block) {
  __shared__ unsigned hist[SEGS + 1];
  for (int i = threadIdx.x; i < SEGS + 1; i += blockDim.x) hist[i] = 0u;
  __syncthreads();

  const long long base = (long long)blockIdx.x * pix_per_block;
  const int b = (int)(base / HW_);
  const int nvec = pix_per_block / 4;
  const int4* lab4 = (const int4*)(labels + base);
  const int4* idx4 = (const int4*)(indexes + base);
  uchar4* seg4 = (uchar4*)(seg + base);

  for (int k = threadIdx.x; k < nvec; k += blockDim.x) {
    int4 l = lab4[k];
    int4 ix = idx4[k];
    int s0 = (l.x == IGNORE_L) ? SEGS : l.x * 32 + ix.x - 1;
    int s1 = (l.y == IGNORE_L) ? SEGS : l.y * 32 + ix.y - 1;
    int s2 = (l.z == IGNORE_L) ? SEGS : l.z * 32 + ix.z - 1;
    int s3 = (l.w == IGNORE_L) ? SEGS : l.w * 32 + ix.w - 1;
    uchar4 sv;
    sv.x = (unsigned char)(s0 == SEGS ? SENT : s0);
    sv.y = (unsigned char)(s1 == SEGS ? SENT : s1);
    sv.z = (unsigned char)(s2 == SEGS ? SENT : s2);
    sv.w = (unsigned char)(s3 == SEGS ? SENT : s3);
    seg4[k] = sv;
    atomicAdd(&hist[s0], 1u);
    atomicAdd(&hist[s1], 1u);
    atomicAdd(&hist[s2], 1u);
    atomicAdd(&hist[s3], 1u);
  }
  __syncthreads();
  for (int i = threadIdx.x; i < SEGS; i += blockDim.x)
    if (hist[i]) atomicAdd(&counts[b * SEGS + i], hist[i]);
}

// ---------------- Pass 2: segment sums via one-hot MFMA GEMM ----------------
// Wave-private coalesced staging: wave w stages AND consumes channels
// [w*32, w*32+32). Per 64-px stage: 8 global loads, each one instruction
// covering 4 rows x 256 B contiguous (8 cache lines/instr, not 64); reg->LDS
// write; B-frags via ds_read_b128 with slot^=(row&15) XOR swizzle. No
// barriers in the main loop. Seg bytes read from global (L1-resident).
__global__ __launch_bounds__(256, 2) void segsum_mfma_kernel(
    const float* __restrict__ feat, const uint8_t* __restrict__ seg,
    float* __restrict__ sums, int chunks_per_img) {
  __shared__ float4 sbuf4[4096];          // 4 waves x 2 bufs x 512 float4

  const int b = blockIdx.x / chunks_per_img;
  const int chunk = blockIdx.x % chunks_per_img;
  const int pbase = chunk * KCHUNK;

  const int l = threadIdx.x & 63;
  const int w = threadIdx.x >> 6;
  const int lane31 = l & 31;
  const int hi = l >> 5;
  const int r15 = lane31 & 15;
  const int ch = w * 32 + lane31;

  // staging addresses: lane covers row (w*32 + i*4 + (l>>4)), bytes (l&15)*16
  const float* fbase =
      feat + ((size_t)(b * 128 + w * 32 + (l >> 4))) * HW_ + pbase + (l & 15) * 4;
  const int wrow = (l >> 4);              // row-within-quad
  const int wcol = (l & 15);              // col slot
  const int wbase = w * 1024;             // float4 units, 2 bufs of 512

  const uint8_t* sgs = seg + (size_t)b * HW_ + pbase;

  unsigned tgt2[MT];
  #pragma unroll
  for (int m = 0; m < MT; ++m) {
    unsigned t = (unsigned)(m * 32 + lane31);
    tgt2[m] = t | (t << 16);
  }

  f32x16 acc[MT];
  #pragma unroll
  for (int m = 0; m < MT; ++m) acc[m] = (f32x16)(0.f);

  #define LOADG(reg, s)                                               \
    do {                                                              \
      _Pragma("unroll") for (int i = 0; i < 8; ++i)                   \
          (reg)[i] = *(const float4*)(fbase + (size_t)(i * 4) * HW_ + \
                                      (s) * SPX);                     \
    } while (0)

  #define WRITE(reg, bsel)                                            \
    do {                                                              \
      _Pragma("unroll") for (int i = 0; i < 8; ++i) {                 \
        int r = i * 4 + wrow;                                         \
        sbuf4[wbase + (bsel)*512 + r * 16 + (wcol ^ (r & 15))] = (reg)[i]; \
      }                                                               \
    } while (0)

  #define KSTEP(f0, f1, sb)                                           \
    do {                                                              \
      unsigned svp[4];                                                \
      _Pragma("unroll") for (int j = 0; j < 4; ++j) {                 \
        unsigned lo8 = (unsigned)(((sb) >> (16 * j)) & 0xFFull);      \
        unsigned hi8 = (unsigned)(((sb) >> (16 * j + 8)) & 0xFFull);  \
        svp[j] = lo8 | (hi8 << 16);                                   \
      }                                                               \
      float fs[8] = {(f0).x, (f0).y, (f0).z, (f0).w,                  \
                     (f1).x, (f1).y, (f1).z, (f1).w};                 \
      union { unsigned u[4]; short8v v; } bhi, blo;                   \
      _Pragma("unroll") for (int j = 0; j < 4; ++j) {                 \
        float2v f2 = {fs[2 * j], fs[2 * j + 1]};                      \
        bf16x2 h2 = __builtin_convertvector(f2, bf16x2);              \
        unsigned hb = __builtin_bit_cast(unsigned, h2);               \
        bhi.u[j] = hb;                                                \
        float fh0 = __builtin_bit_cast(float, hb << 16);              \
        float fh1 = __builtin_bit_cast(float, hb & 0xFFFF0000u);      \
        float2v l2 = {f2.x - fh0, f2.y - fh1};                        \
        bf16x2 lo2 = __builtin_convertvector(l2, bf16x2);             \
        blo.u[j] = __builtin_bit_cast(unsigned, lo2);                 \
      }                                                               \
      _Pragma("unroll") for (int m = 0; m < MT; ++m) {                \
        union { unsigned u[4]; short8v v; } a;                        \
        _Pragma("unroll") for (int j = 0; j < 4; ++j) {               \
          u16x2 y = __builtin_bit_cast(u16x2, svp[j] ^ tgt2[m]);      \
          u16x2 nz = __builtin_elementwise_min(y, (u16x2)(unsigned short)1); \
          u16x2 msk = nz - (u16x2)(unsigned short)1;                  \
          u16x2 av = msk & (u16x2)(unsigned short)0x3F80;             \
          a.u[j] = __builtin_bit_cast(unsigned, av);                  \
        }                                                             \
        acc[m] = __builtin_amdgcn_mfma_f32_32x32x16_bf16(a.v, bhi.v,  \
                                                         acc[m], 0, 0, 0); \
        acc[m] = __builtin_amdgcn_mfma_f32_32x32x16_bf16(a.v, blo.v,  \
                                                         acc[m], 0, 0, 0); \
      }                                                               \
    } while (0)

  // consume stage s from buffer bsel: 4 ksteps of 16 px
  #define CONSUME(bsel, s)                                            \
    do {                                                              \
      const uint8_t* sg = sgs + (s)*SPX;                              \
      _Pragma("unroll") for (int j = 0; j < 4; ++j) {                 \
        int c = j * 4 + hi * 2;                                       \
        float4 f0 = sbuf4[wbase + (bsel)*512 + lane31 * 16 + (c ^ r15)]; \
        float4 f1 =                                                   \
            sbuf4[wbase + (bsel)*512 + lane31 * 16 + ((c + 1) ^ r15)]; \
        unsigned long long sb =                                       \
            *(const unsigned long long*)(sg + j * 16 + hi * 8);       \
        KSTEP(f0, f1, sb);                                            \
      }                                                               \
    } while (0)

  float4 reg[8];
  LOADG(reg, 0);
  WRITE(reg, 0);
  LOADG(reg, 1);
  for (int s = 0; s < NST; ++s) {
    CONSUME(s & 1, s);
    if (s + 1 < NST) {
      WRITE(reg, (s + 1) & 1);
      if (s + 2 < NST) LOADG(reg, s + 2);
    }
  }

  // epilogue: C/D layout col=lane&31, row=(r&3)+8*(r>>2)+4*hi
  #pragma unroll
  for (int m = 0; m < MT; ++m) {
    #pragma unroll
    for (int r = 0; r < 16; ++r) {
      int s = m * 32 + (r & 3) + 8 * (r >> 2) + 4 * hi;
      float v = acc[m][r];
      if (v != 0.f)
        atomicAdd(&sums[((size_t)b * SEGS + s) * 128 + ch], v);
    }
  }
}

// ---------------- Pass 3: per-(image,class) pairwise loss ----------------
__global__ __launch_bounds__(256) void pairloss_kernel(
    const float* __restrict__ sums, const unsigned* __restrict__ counts,
    float* __restrict__ loss_sum, unsigned* __restrict__ nvalid, int D) {
  const int b = blockIdx.x / NC;
  const int c = blockIdx.x % NC;

  __shared__ float sh_mean[32 * 128];
  __shared__ float sh_cnt[33];
  __shared__ int list[33];
  __shared__ int Ksh;
  __shared__ uchar2 pairs[32 * 31 / 2];
  __shared__ double wred[4];

  if (threadIdx.x == 0) {
    int K = 0;
    for (int ii = 0; ii < 32; ++ii) {
      unsigned cnt = counts[b * SEGS + c * 32 + ii];
      if (cnt >= 2u) {
        list[K] = ii;
        sh_cnt[K] = (float)cnt;
        ++K;
      }
    }
    Ksh = K;
    int p = 0;
    for (int i = 0; i < K; ++i)
      for (int j = i + 1; j < K; ++j) {
        pairs[p].x = (unsigned char)i;
        pairs[p].y = (unsigned char)j;
        ++p;
      }
  }
  __syncthreads();
  const int K = Ksh;
  if (K == 0) return;

  for (int idx = threadIdx.x; idx < K * D; idx += blockDim.x) {
    int k = idx / 128, d = idx % 128;
    int s = c * 32 + list[k];
    sh_mean[k * 128 + d] = sums[((size_t)b * SEGS + s) * D + d] / sh_cnt[k];
  }
  __syncthreads();

  const int npairs = K * (K - 1) / 2;
  const int total = npairs * 128;
  float local = 0.f;
  for (int idx = threadIdx.x; idx < total; idx += blockDim.x) {
    int p = idx >> 7, d = idx & 127;
    int i = pairs[p].x, j = pairs[p].y;
    local += fabsf(sh_mean[i * 128 + d] - sh_mean[j * 128 + d]);
  }

  double v = (double)local;
  #pragma unroll
  for (int off = 32; off; off >>= 1) v += __shfl_down(v, off, 64);
  const int wave = threadIdx.x >> 6;
  if ((threadIdx.x & 63) == 0) wred[wave] = v;
  __syncthreads();
  if (threadIdx.x == 0) {
    double ssum = 2.0 * (wred[0] + wred[1] + wred[2] + wred[3]);
    double ret = ssum / ((double)K * (double)K * (double)D);
    double loss = (ret < 1.0) ? 0.5 * ret * ret : ret - 0.5;
    atomicAdd(loss_sum, (float)loss);
    atomicAdd(nvalid, 1u);
  }
}

// ---------------- Pass 4: finalize ----------------
__global__ void finalize_kernel(const float* __restrict__ loss_sum,
                                const unsigned* __restrict__ nvalid,
                                float* __restrict__ out, int B) {
  if (threadIdx.x == 0) {
    unsigned n = *nvalid;
    out[0] = n ? (*loss_sum / (float)n) / (float)B : 0.f;
  }
}

extern "C" void kernel_launch(void* const* d_in, const int* in_sizes, int n_in,
                              void* d_out, int out_size, void* d_ws,
                              size_t ws_size, hipStream_t stream) {
  const float* feat = (const float*)d_in[0];
  const int* labels = (const int*)d_in[1];
  const int* indexes = (const int*)d_in[2];

  const int npix_total = in_sizes[1];          // B*H*W
  const int B = npix_total / HW_;              // 8
  const int D = in_sizes[0] / npix_total;      // 128
  const int cpi = HW_ / KCHUNK;                // 128 chunks per image

  uint8_t* seg = (uint8_t*)d_ws;
  size_t off = ((size_t)npix_total + 255) & ~(size_t)255;
  float* sums = (float*)((char*)d_ws + off);
  size_t sums_bytes = (size_t)B * TILE * sizeof(float);
  unsigned* counts = (unsigned*)((char*)d_ws + off + sums_bytes);
  size_t counts_bytes = (size_t)B * SEGS * sizeof(unsigned);
  float* loss_sum = (float*)((char*)d_ws + off + sums_bytes + counts_bytes);
  unsigned* nvalid = (unsigned*)(loss_sum + 1);

  hipMemsetAsync(sums, 0, sums_bytes + counts_bytes + 2 * sizeof(unsigned),
                 stream);

  const int pix_per_block = 4096;
  seg_count_kernel<<<npix_total / pix_per_block, 256, 0, stream>>>(
      labels, indexes, seg, counts, pix_per_block);

  segsum_mfma_kernel<<<B * cpi, 256, 0, stream>>>(feat, seg, sums, cpi);

  pairloss_kernel<<<B * NC, 256, 0, stream>>>(sums, counts, loss_sum, nvalid,
                                              D);
  finalize_kernel<<<1, 64, 0, stream>>>(loss_sum, nvalid, (float*)d_out, B);
}

// Round 11
// 419.011 us; speedup vs baseline: 1.2508x; 1.2508x over previous
//
#include <hip/hip_runtime.h>
#include <stdint.h>

#define NC 5
#define SEGS 160            // remapped: label*32 + (idx-1), idx in [1,32]
#define MT 5                // 5 M-tiles of 32
#define HW_ (512 * 512)
#define IGNORE_L 255
#define SENT 0xFF
#define KCHUNK 2048         // pixels per segsum block
#define NU (KCHUNK / 64)    // 32 units; unit = 32 px/lane = 128 B contiguous
#define TILE (SEGS * 128)

typedef __attribute__((ext_vector_type(8))) short short8v;
typedef __attribute__((ext_vector_type(16))) float f32x16;
typedef __attribute__((ext_vector_type(2))) unsigned short u16x2;
typedef __attribute__((ext_vector_type(2))) float float2v;
typedef __attribute__((ext_vector_type(2))) __bf16 bf16x2;
typedef __attribute__((ext_vector_type(2))) unsigned long long u64x2;

// ---------------- Pass 1: remapped seg ids + counts ----------------
__global__ __launch_bounds__(256) void seg_count_kernel(
    const int* __restrict__ labels, const int* __restrict__ indexes,
    uint8_t* __restrict__ seg, unsigned* __restrict__ counts,
    int pix_per_block) {
  __shared__ unsigned hist[SEGS + 1];
  for (int i = threadIdx.x; i < SEGS + 1; i += blockDim.x) hist[i] = 0u;
  __syncthreads();

  const long long base = (long long)blockIdx.x * pix_per_block;
  const int b = (int)(base / HW_);
  const int nvec = pix_per_block / 4;
  const int4* lab4 = (const int4*)(labels + base);
  const int4* idx4 = (const int4*)(indexes + base);
  uchar4* seg4 = (uchar4*)(seg + base);

  for (int k = threadIdx.x; k < nvec; k += blockDim.x) {
    int4 l = lab4[k];
    int4 ix = idx4[k];
    int s0 = (l.x == IGNORE_L) ? SEGS : l.x * 32 + ix.x - 1;
    int s1 = (l.y == IGNORE_L) ? SEGS : l.y * 32 + ix.y - 1;
    int s2 = (l.z == IGNORE_L) ? SEGS : l.z * 32 + ix.z - 1;
    int s3 = (l.w == IGNORE_L) ? SEGS : l.w * 32 + ix.w - 1;
    uchar4 sv;
    sv.x = (unsigned char)(s0 == SEGS ? SENT : s0);
    sv.y = (unsigned char)(s1 == SEGS ? SENT : s1);
    sv.z = (unsigned char)(s2 == SEGS ? SENT : s2);
    sv.w = (unsigned char)(s3 == SEGS ? SENT : s3);
    seg4[k] = sv;
    atomicAdd(&hist[s0], 1u);
    atomicAdd(&hist[s1], 1u);
    atomicAdd(&hist[s2], 1u);
    atomicAdd(&hist[s3], 1u);
  }
  __syncthreads();
  for (int i = threadIdx.x; i < SEGS; i += blockDim.x)
    if (hist[i]) atomicAdd(&counts[b * SEGS + i], hist[i]);
}

// ---------------- Pass 2: segment sums via one-hot MFMA GEMM ----------------
// R9 skeleton (2-deep register pipeline, per-channel-row loads, LDS-staged seg
// bytes, atomic epilogue) with: 8-float4 buffers (unit = 128 B line; lane's
// per-superstep address run stays 256 B contiguous), v_perm seg expansion,
// tgt folded into svp, __launch_bounds__(256,3) targeting 3 waves/SIMD.
__global__ __launch_bounds__(256, 3) void segsum_mfma_kernel(
    const float* __restrict__ feat, const uint8_t* __restrict__ seg,
    float* __restrict__ sums, int chunks_per_img) {
  __shared__ unsigned long long sseg8[KCHUNK / 8];
  const int b = blockIdx.x / chunks_per_img;
  const int chunk = blockIdx.x % chunks_per_img;
  const int pbase = chunk * KCHUNK;

  const unsigned long long* gseg8 =
      (const unsigned long long*)(seg + (size_t)b * HW_ + pbase);
  sseg8[threadIdx.x] = gseg8[threadIdx.x];
  __syncthreads();

  const int l = threadIdx.x & 63;
  const int w = threadIdx.x >> 6;
  const int lane31 = l & 31;
  const int hi = l >> 5;
  const int ch = w * 32 + lane31;
  const int hi16 = hi * 16;               // float4 offset of half-run
  const unsigned lane2 = (unsigned)lane31 | ((unsigned)lane31 << 16);

  const float4* fp4 = (const float4*)(feat + ((size_t)b * 128 + ch) * HW_ + pbase);
  const uint8_t* segb = (const uint8_t*)sseg8 + hi * 64;

  f32x16 acc[MT];
  #pragma unroll
  for (int m = 0; m < MT; ++m) acc[m] = (f32x16)(0.f);

  // unit u: lane reads px [(u>>1)*128 + hi*64 + (u&1)*32, +32) = 8 float4
  #define LOADU(buf, u)                                               \
    do {                                                              \
      const float4* p = fp4 + ((u) >> 1) * 32 + hi16 + ((u)&1) * 8;   \
      _Pragma("unroll") for (int i = 0; i < 8; ++i) (buf)[i] = p[i];  \
    } while (0)

  #define KSTEP(f0, f1, sb)                                           \
    do {                                                              \
      unsigned slo = (unsigned)(sb);                                  \
      unsigned shi = (unsigned)((sb) >> 32);                          \
      unsigned svp[4];                                                \
      svp[0] = __builtin_amdgcn_perm(0u, slo, 0x0C010C00u) ^ lane2;   \
      svp[1] = __builtin_amdgcn_perm(0u, slo, 0x0C030C02u) ^ lane2;   \
      svp[2] = __builtin_amdgcn_perm(0u, shi, 0x0C010C00u) ^ lane2;   \
      svp[3] = __builtin_amdgcn_perm(0u, shi, 0x0C030C02u) ^ lane2;   \
      float fs[8] = {(f0).x, (f0).y, (f0).z, (f0).w,                  \
                     (f1).x, (f1).y, (f1).z, (f1).w};                 \
      union { unsigned u[4]; short8v v; } bhi, blo;                   \
      _Pragma("unroll") for (int j = 0; j < 4; ++j) {                 \
        float2v f2 = {fs[2 * j], fs[2 * j + 1]};                      \
        bf16x2 h2 = __builtin_convertvector(f2, bf16x2);              \
        unsigned hb = __builtin_bit_cast(unsigned, h2);               \
        bhi.u[j] = hb;                                                \
        float fh0 = __builtin_bit_cast(float, hb << 16);              \
        float fh1 = __builtin_bit_cast(float, hb & 0xFFFF0000u);      \
        float2v l2 = {f2.x - fh0, f2.y - fh1};                        \
        bf16x2 lo2 = __builtin_convertvector(l2, bf16x2);             \
        blo.u[j] = __builtin_bit_cast(unsigned, lo2);                 \
      }                                                               \
      _Pragma("unroll") for (int m = 0; m < MT; ++m) {                \
        const unsigned m2 = (unsigned)(m * 32) * 0x10001u;            \
        union { unsigned u[4]; short8v v; } a;                        \
        _Pragma("unroll") for (int j = 0; j < 4; ++j) {               \
          u16x2 y = __builtin_bit_cast(u16x2, svp[j] ^ m2);           \
          u16x2 nz = __builtin_elementwise_min(y, (u16x2)(unsigned short)1); \
          u16x2 msk = nz - (u16x2)(unsigned short)1;                  \
          u16x2 av = msk & (u16x2)(unsigned short)0x3F80;             \
          a.u[j] = __builtin_bit_cast(unsigned, av);                  \
        }                                                             \
        acc[m] = __builtin_amdgcn_mfma_f32_32x32x16_bf16(a.v, bhi.v,  \
                                                         acc[m], 0, 0, 0); \
        acc[m] = __builtin_amdgcn_mfma_f32_32x32x16_bf16(a.v, blo.v,  \
                                                         acc[m], 0, 0, 0); \
      }                                                               \
    } while (0)

  // consume unit u from an 8-float4 buffer: 4 ksteps of 8 px/lane
  #define CONSUME(buf, u)                                             \
    do {                                                              \
      const uint8_t* sgu = segb + ((u) >> 1) * 128 + ((u)&1) * 32;    \
      u64x2 ga = *(const u64x2*)(sgu);                                \
      u64x2 gb = *(const u64x2*)(sgu + 16);                           \
      KSTEP((buf)[0], (buf)[1], ga.x);                                \
      KSTEP((buf)[2], (buf)[3], ga.y);                                \
      KSTEP((buf)[4], (buf)[5], gb.x);                                \
      KSTEP((buf)[6], (buf)[7], gb.y);                                \
    } while (0)

  float4 bufX[8], bufY[8];
  LOADU(bufX, 0);
  LOADU(bufY, 1);
  for (int u = 0; u < NU; u += 2) {
    CONSUME(bufX, u);
    if (u + 2 < NU) LOADU(bufX, u + 2);
    CONSUME(bufY, u + 1);
    if (u + 3 < NU) LOADU(bufY, u + 3);
  }

  // epilogue: C/D layout col=lane&31, row=(r&3)+8*(r>>2)+4*hi
  #pragma unroll
  for (int m = 0; m < MT; ++m) {
    #pragma unroll
    for (int r = 0; r < 16; ++r) {
      int s = m * 32 + (r & 3) + 8 * (r >> 2) + 4 * hi;
      float v = acc[m][r];
      if (v != 0.f)
        atomicAdd(&sums[((size_t)b * SEGS + s) * 128 + ch], v);
    }
  }
}

// ---------------- Pass 3: per-(image,class) pairwise loss ----------------
__global__ __launch_bounds__(256) void pairloss_kernel(
    const float* __restrict__ sums, const unsigned* __restrict__ counts,
    float* __restrict__ loss_sum, unsigned* __restrict__ nvalid, int D) {
  const int b = blockIdx.x / NC;
  const int c = blockIdx.x % NC;

  __shared__ float sh_mean[32 * 128];
  __shared__ float sh_cnt[33];
  __shared__ int list[33];
  __shared__ int Ksh;
  __shared__ uchar2 pairs[32 * 31 / 2];
  __shared__ double wred[4];

  if (threadIdx.x == 0) {
    int K = 0;
    for (int ii = 0; ii < 32; ++ii) {
      unsigned cnt = counts[b * SEGS + c * 32 + ii];
      if (cnt >= 2u) {
        list[K] = ii;
        sh_cnt[K] = (float)cnt;
        ++K;
      }
    }
    Ksh = K;
    int p = 0;
    for (int i = 0; i < K; ++i)
      for (int j = i + 1; j < K; ++j) {
        pairs[p].x = (unsigned char)i;
        pairs[p].y = (unsigned char)j;
        ++p;
      }
  }
  __syncthreads();
  const int K = Ksh;
  if (K == 0) return;

  for (int idx = threadIdx.x; idx < K * D; idx += blockDim.x) {
    int k = idx / 128, d = idx % 128;
    int s = c * 32 + list[k];
    sh_mean[k * 128 + d] = sums[((size_t)b * SEGS + s) * D + d] / sh_cnt[k];
  }
  __syncthreads();

  const int npairs = K * (K - 1) / 2;
  const int total = npairs * 128;
  float local = 0.f;
  for (int idx = threadIdx.x; idx < total; idx += blockDim.x) {
    int p = idx >> 7, d = idx & 127;
    int i = pairs[p].x, j = pairs[p].y;
    local += fabsf(sh_mean[i * 128 + d] - sh_mean[j * 128 + d]);
  }

  double v = (double)local;
  #pragma unroll
  for (int off = 32; off; off >>= 1) v += __shfl_down(v, off, 64);
  const int wave = threadIdx.x >> 6;
  if ((threadIdx.x & 63) == 0) wred[wave] = v;
  __syncthreads();
  if (threadIdx.x == 0) {
    double ssum = 2.0 * (wred[0] + wred[1] + wred[2] + wred[3]);
    double ret = ssum / ((double)K * (double)K * (double)D);
    double loss = (ret < 1.0) ? 0.5 * ret * ret : ret - 0.5;
    atomicAdd(loss_sum, (float)loss);
    atomicAdd(nvalid, 1u);
  }
}

// ---------------- Pass 4: finalize ----------------
__global__ void finalize_kernel(const float* __restrict__ loss_sum,
                                const unsigned* __restrict__ nvalid,
                                float* __restrict__ out, int B) {
  if (threadIdx.x == 0) {
    unsigned n = *nvalid;
    out[0] = n ? (*loss_sum / (float)n) / (float)B : 0.f;
  }
}

extern "C" void kernel_launch(void* const* d_in, const int* in_sizes, int n_in,
                              void* d_out, int out_size, void* d_ws,
                              size_t ws_size, hipStream_t stream) {
  const float* feat = (const float*)d_in[0];
  const int* labels = (const int*)d_in[1];
  const int* indexes = (const int*)d_in[2];

  const int npix_total = in_sizes[1];          // B*H*W
  const int B = npix_total / HW_;              // 8
  const int D = in_sizes[0] / npix_total;      // 128
  const int cpi = HW_ / KCHUNK;                // 128 chunks per image

  uint8_t* seg = (uint8_t*)d_ws;
  size_t off = ((size_t)npix_total + 255) & ~(size_t)255;
  float* sums = (float*)((char*)d_ws + off);
  size_t sums_bytes = (size_t)B * TILE * sizeof(float);
  unsigned* counts = (unsigned*)((char*)d_ws + off + sums_bytes);
  size_t counts_bytes = (size_t)B * SEGS * sizeof(unsigned);
  float* loss_sum = (float*)((char*)d_ws + off + sums_bytes + counts_bytes);
  unsigned* nvalid = (unsigned*)(loss_sum + 1);

  hipMemsetAsync(sums, 0, sums_bytes + counts_bytes + 2 * sizeof(unsigned),
                 stream);

  const int pix_per_block = 4096;
  seg_count_kernel<<<npix_total / pix_per_block, 256, 0, stream>>>(
      labels, indexes, seg, counts, pix_per_block);

  segsum_mfma_kernel<<<B * cpi, 256, 0, stream>>>(feat, seg, sums, cpi);

  pairloss_kernel<<<B * NC, 256, 0, stream>>>(sums, counts, loss_sum, nvalid,
                                              D);
  finalize_kernel<<<1, 64, 0, stream>>>(loss_sum, nvalid, (float*)d_out, B);
}

// Round 12
// 336.367 us; speedup vs baseline: 1.5582x; 1.2457x over previous
//
#include <hip/hip_runtime.h>
#include <stdint.h>

#define NC 5
#define SEGS 160            // remapped: label*32 + (idx-1), idx in [1,32]
#define MT 5                // 5 M-tiles of 32
#define HW_ (512 * 512)
#define IGNORE_L 255
#define SENT 0xFF
#define KCHUNK 2048         // pixels per segsum block
#define NSTG 64             // 32-px stages
#define SLOTB 4096          // LDS bytes per stage slot (32 ch x 128 B)
#define WLDSB (3 * SLOTB)   // 3-slot ring per wave
#define TILE (SEGS * 128)

typedef __attribute__((ext_vector_type(8))) short short8v;
typedef __attribute__((ext_vector_type(16))) float f32x16;
typedef __attribute__((ext_vector_type(2))) unsigned short u16x2;
typedef __attribute__((ext_vector_type(2))) float float2v;
typedef __attribute__((ext_vector_type(2))) __bf16 bf16x2;

// ---------------- Pass 1: remapped seg ids + counts ----------------
__global__ __launch_bounds__(256) void seg_count_kernel(
    const int* __restrict__ labels, const int* __restrict__ indexes,
    uint8_t* __restrict__ seg, unsigned* __restrict__ counts,
    int pix_per_block) {
  __shared__ unsigned hist[SEGS + 1];
  for (int i = threadIdx.x; i < SEGS + 1; i += blockDim.x) hist[i] = 0u;
  __syncthreads();

  const long long base = (long long)blockIdx.x * pix_per_block;
  const int b = (int)(base / HW_);
  const int nvec = pix_per_block / 4;
  const int4* lab4 = (const int4*)(labels + base);
  const int4* idx4 = (const int4*)(indexes + base);
  uchar4* seg4 = (uchar4*)(seg + base);

  for (int k = threadIdx.x; k < nvec; k += blockDim.x) {
    int4 l = lab4[k];
    int4 ix = idx4[k];
    int s0 = (l.x == IGNORE_L) ? SEGS : l.x * 32 + ix.x - 1;
    int s1 = (l.y == IGNORE_L) ? SEGS : l.y * 32 + ix.y - 1;
    int s2 = (l.z == IGNORE_L) ? SEGS : l.z * 32 + ix.z - 1;
    int s3 = (l.w == IGNORE_L) ? SEGS : l.w * 32 + ix.w - 1;
    uchar4 sv;
    sv.x = (unsigned char)(s0 == SEGS ? SENT : s0);
    sv.y = (unsigned char)(s1 == SEGS ? SENT : s1);
    sv.z = (unsigned char)(s2 == SEGS ? SENT : s2);
    sv.w = (unsigned char)(s3 == SEGS ? SENT : s3);
    seg4[k] = sv;
    atomicAdd(&hist[s0], 1u);
    atomicAdd(&hist[s1], 1u);
    atomicAdd(&hist[s2], 1u);
    atomicAdd(&hist[s3], 1u);
  }
  __syncthreads();
  for (int i = threadIdx.x; i < SEGS; i += blockDim.x)
    if (hist[i]) atomicAdd(&counts[b * SEGS + i], hist[i]);
}

// ---------------- Pass 2: segment sums via one-hot MFMA GEMM ----------------
// Wave-private DMA pipeline: per 32-px stage, 4x global_load_lds (1 KB each;
// 8 channel rows x 128 B contiguous => 16 cache lines/instr). Source px
// chunks pre-swizzled (chunk j of ch holds global chunk j^(ch&7)) so the
// ds_read_b128 consume path is bank-spread; LDS dest stays lane-linear.
// 3-slot ring, counted vmcnt(8) (never 0 until tail), no block barriers in
// the loop. acc in 80 VGPR (MT=5); no staging regs -> 3 waves/SIMD.
__global__ __launch_bounds__(256, 3) void segsum_mfma_kernel(
    const float* __restrict__ feat, const uint8_t* __restrict__ seg,
    float* __restrict__ sums, int chunks_per_img) {
  __shared__ __align__(16) char dmabuf[4 * WLDSB];       // 48 KB
  __shared__ unsigned long long sseg8[KCHUNK / 8];       // 2 KB

  const int b = blockIdx.x / chunks_per_img;
  const int chunk = blockIdx.x % chunks_per_img;
  const int pbase = chunk * KCHUNK;

  const unsigned long long* gseg8 =
      (const unsigned long long*)(seg + (size_t)b * HW_ + pbase);
  sseg8[threadIdx.x] = gseg8[threadIdx.x];
  __syncthreads();   // sseg8 is block-shared; dmabuf is wave-private

  const int l = threadIdx.x & 63;
  const int w = threadIdx.x >> 6;
  const int lane31 = l & 31;
  const int hi = l >> 5;
  const int ch = w * 32 + lane31;
  const int swz = l & 7;                       // ch&7 for consume path
  const unsigned lane2 = (unsigned)lane31 | ((unsigned)lane31 << 16);

  char* wlds = dmabuf + w * WLDSB;
  // DMA source: lane covers channel (w*32 + (l>>3)), px chunk ((l&7)^((l>>3)&7))
  const float* gdma = feat +
      ((size_t)(b * 128 + w * 32 + (l >> 3))) * HW_ + pbase +
      (((l & 7) ^ ((l >> 3) & 7)) << 2);

  f32x16 acc[MT];
  #pragma unroll
  for (int m = 0; m < MT; ++m) acc[m] = (f32x16)(0.f);

  #define ISSUE(s, slot)                                               \
    do {                                                               \
      _Pragma("unroll") for (int i = 0; i < 4; ++i) {                  \
        __builtin_amdgcn_global_load_lds(                              \
            (const __attribute__((address_space(1))) void*)(const void*)( \
                gdma + (size_t)i * 8 * HW_ + (s)*32),                  \
            (__attribute__((address_space(3))) void*)(void*)(          \
                wlds + (slot)*SLOTB + i * 1024),                       \
            16, 0, 0);                                                 \
      }                                                                \
    } while (0)

  #define WAITV(n)                                                    \
    do {                                                               \
      asm volatile("s_waitcnt vmcnt(" #n ")" ::: "memory");            \
      __builtin_amdgcn_sched_barrier(0);                               \
    } while (0)

  #define KSTEP(f0, f1, sb)                                            \
    do {                                                               \
      unsigned slo = (unsigned)(sb);                                   \
      unsigned shi = (unsigned)((sb) >> 32);                           \
      unsigned svp[4];                                                 \
      svp[0] = __builtin_amdgcn_perm(0u, slo, 0x0C010C00u) ^ lane2;    \
      svp[1] = __builtin_amdgcn_perm(0u, slo, 0x0C030C02u) ^ lane2;    \
      svp[2] = __builtin_amdgcn_perm(0u, shi, 0x0C010C00u) ^ lane2;    \
      svp[3] = __builtin_amdgcn_perm(0u, shi, 0x0C030C02u) ^ lane2;    \
      float fs[8] = {(f0).x, (f0).y, (f0).z, (f0).w,                   \
                     (f1).x, (f1).y, (f1).z, (f1).w};                  \
      union { unsigned u[4]; short8v v; } bhi, blo;                    \
      _Pragma("unroll") for (int j = 0; j < 4; ++j) {                  \
        float2v f2 = {fs[2 * j], fs[2 * j + 1]};                       \
        bf16x2 h2 = __builtin_convertvector(f2, bf16x2);               \
        unsigned hb = __builtin_bit_cast(unsigned, h2);                \
        bhi.u[j] = hb;                                                 \
        float fh0 = __builtin_bit_cast(float, hb << 16);               \
        float fh1 = __builtin_bit_cast(float, hb & 0xFFFF0000u);       \
        float2v l2 = {f2.x - fh0, f2.y - fh1};                         \
        bf16x2 lo2 = __builtin_convertvector(l2, bf16x2);              \
        blo.u[j] = __builtin_bit_cast(unsigned, lo2);                  \
      }                                                                \
      _Pragma("unroll") for (int m = 0; m < MT; ++m) {                 \
        const unsigned m2 = (unsigned)(m * 32) * 0x10001u;             \
        union { unsigned u[4]; short8v v; } a;                         \
        _Pragma("unroll") for (int j = 0; j < 4; ++j) {                \
          u16x2 y = __builtin_bit_cast(u16x2, svp[j] ^ m2);            \
          u16x2 nz = __builtin_elementwise_min(y, (u16x2)(unsigned short)1); \
          u16x2 msk = nz - (u16x2)(unsigned short)1;                   \
          u16x2 av = msk & (u16x2)(unsigned short)0x3F80;              \
          a.u[j] = __builtin_bit_cast(unsigned, av);                   \
        }                                                              \
        acc[m] = __builtin_amdgcn_mfma_f32_32x32x16_bf16(a.v, bhi.v,   \
                                                         acc[m], 0, 0, 0); \
        acc[m] = __builtin_amdgcn_mfma_f32_32x32x16_bf16(a.v, blo.v,   \
                                                         acc[m], 0, 0, 0); \
      }                                                                \
    } while (0)

  // consume stage s from ring slot: 2 ksteps of 16 px
  #define CONSUME(s, slot)                                             \
    do {                                                               \
      const char* cb = wlds + (slot)*SLOTB + lane31 * 128;             \
      {                                                                \
        int c0 = hi * 2;                                               \
        float4 f0 = *(const float4*)(cb + ((c0)&7 ^ swz) * 16 + ((c0)&8) * 16); \
        float4 f1 = *(const float4*)(cb + ((c0 + 1) ^ swz) * 16);      \
        unsigned long long sbv = sseg8[(s)*4 + hi];                    \
        KSTEP(f0, f1, sbv);                                            \
      }                                                                \
      {                                                                \
        int c0 = 4 + hi * 2;                                           \
        float4 f0 = *(const float4*)(cb + ((c0) ^ swz) * 16);          \
        float4 f1 = *(const float4*)(cb + ((c0 + 1) ^ swz) * 16);      \
        unsigned long long sbv = sseg8[(s)*4 + 2 + hi];                \
        KSTEP(f0, f1, sbv);                                            \
      }                                                                \
    } while (0)

  // NOTE: chunk indices c0..c0+1 are in [0,8); XOR with swz stays in [0,8).
  #undef CONSUME
  #define CONSUME(s, slot)                                             \
    do {                                                               \
      const char* cb = wlds + (slot)*SLOTB + lane31 * 128;             \
      {                                                                \
        int c0 = hi * 2;                                               \
        float4 f0 = *(const float4*)(cb + ((c0) ^ swz) * 16);          \
        float4 f1 = *(const float4*)(cb + ((c0 + 1) ^ swz) * 16);      \
        unsigned long long sbv = sseg8[(s)*4 + hi];                    \
        KSTEP(f0, f1, sbv);                                            \
      }                                                                \
      {                                                                \
        int c0 = 4 + hi * 2;                                           \
        float4 f0 = *(const float4*)(cb + ((c0) ^ swz) * 16);          \
        float4 f1 = *(const float4*)(cb + ((c0 + 1) ^ swz) * 16);      \
        unsigned long long sbv = sseg8[(s)*4 + 2 + hi];                \
        KSTEP(f0, f1, sbv);                                            \
      }                                                                \
    } while (0)

  ISSUE(0, 0);
  ISSUE(1, 1);
  ISSUE(2, 2);

  int s = 0;
  #pragma unroll 1
  for (int g = 0; g < 20; ++g) {           // stages 0..59
    WAITV(8); CONSUME(s, 0); ISSUE(s + 3, 0);
    WAITV(8); CONSUME(s + 1, 1); ISSUE(s + 4, 1);
    WAITV(8); CONSUME(s + 2, 2); ISSUE(s + 5, 2);
    s += 3;
  }
  WAITV(8); CONSUME(60, 0); ISSUE(63, 0);  // 63 % 3 == 0
  WAITV(8); CONSUME(61, 1);
  WAITV(4); CONSUME(62, 2);
  WAITV(0); CONSUME(63, 0);

  // epilogue: C/D layout col=lane&31, row=(r&3)+8*(r>>2)+4*hi
  #pragma unroll
  for (int m = 0; m < MT; ++m) {
    #pragma unroll
    for (int r = 0; r < 16; ++r) {
      int sg = m * 32 + (r & 3) + 8 * (r >> 2) + 4 * hi;
      float v = acc[m][r];
      if (v != 0.f)
        atomicAdd(&sums[((size_t)b * SEGS + sg) * 128 + ch], v);
    }
  }
}

// ---------------- Pass 3: per-(image,class) pairwise loss ----------------
__global__ __launch_bounds__(256) void pairloss_kernel(
    const float* __restrict__ sums, const unsigned* __restrict__ counts,
    float* __restrict__ loss_sum, unsigned* __restrict__ nvalid, int D) {
  const int b = blockIdx.x / NC;
  const int c = blockIdx.x % NC;

  __shared__ float sh_mean[32 * 128];
  __shared__ float sh_cnt[33];
  __shared__ int list[33];
  __shared__ int Ksh;
  __shared__ uchar2 pairs[32 * 31 / 2];
  __shared__ double wred[4];

  if (threadIdx.x == 0) {
    int K = 0;
    for (int ii = 0; ii < 32; ++ii) {
      unsigned cnt = counts[b * SEGS + c * 32 + ii];
      if (cnt >= 2u) {
        list[K] = ii;
        sh_cnt[K] = (float)cnt;
        ++K;
      }
    }
    Ksh = K;
    int p = 0;
    for (int i = 0; i < K; ++i)
      for (int j = i + 1; j < K; ++j) {
        pairs[p].x = (unsigned char)i;
        pairs[p].y = (unsigned char)j;
        ++p;
      }
  }
  __syncthreads();
  const int K = Ksh;
  if (K == 0) return;

  for (int idx = threadIdx.x; idx < K * D; idx += blockDim.x) {
    int k = idx / 128, d = idx % 128;
    int s = c * 32 + list[k];
    sh_mean[k * 128 + d] = sums[((size_t)b * SEGS + s) * D + d] / sh_cnt[k];
  }
  __syncthreads();

  const int npairs = K * (K - 1) / 2;
  const int total = npairs * 128;
  float local = 0.f;
  for (int idx = threadIdx.x; idx < total; idx += blockDim.x) {
    int p = idx >> 7, d = idx & 127;
    int i = pairs[p].x, j = pairs[p].y;
    local += fabsf(sh_mean[i * 128 + d] - sh_mean[j * 128 + d]);
  }

  double v = (double)local;
  #pragma unroll
  for (int off = 32; off; off >>= 1) v += __shfl_down(v, off, 64);
  const int wave = threadIdx.x >> 6;
  if ((threadIdx.x & 63) == 0) wred[wave] = v;
  __syncthreads();
  if (threadIdx.x == 0) {
    double ssum = 2.0 * (wred[0] + wred[1] + wred[2] + wred[3]);
    double ret = ssum / ((double)K * (double)K * (double)D);
    double loss = (ret < 1.0) ? 0.5 * ret * ret : ret - 0.5;
    atomicAdd(loss_sum, (float)loss);
    atomicAdd(nvalid, 1u);
  }
}

// ---------------- Pass 4: finalize ----------------
__global__ void finalize_kernel(const float* __restrict__ loss_sum,
                                const unsigned* __restrict__ nvalid,
                                float* __restrict__ out, int B) {
  if (threadIdx.x == 0) {
    unsigned n = *nvalid;
    out[0] = n ? (*loss_sum / (float)n) / (float)B : 0.f;
  }
}

extern "C" void kernel_launch(void* const* d_in, const int* in_sizes, int n_in,
                              void* d_out, int out_size, void* d_ws,
                              size_t ws_size, hipStream_t stream) {
  const float* feat = (const float*)d_in[0];
  const int* labels = (const int*)d_in[1];
  const int* indexes = (const int*)d_in[2];

  const int npix_total = in_sizes[1];          // B*H*W
  const int B = npix_total / HW_;              // 8
  const int D = in_sizes[0] / npix_total;      // 128
  const int cpi = HW_ / KCHUNK;                // 128 chunks per image

  uint8_t* seg = (uint8_t*)d_ws;
  size_t off = ((size_t)npix_total + 255) & ~(size_t)255;
  float* sums = (float*)((char*)d_ws + off);
  size_t sums_bytes = (size_t)B * TILE * sizeof(float);
  unsigned* counts = (unsigned*)((char*)d_ws + off + sums_bytes);
  size_t counts_bytes = (size_t)B * SEGS * sizeof(unsigned);
  float* loss_sum = (float*)((char*)d_ws + off + sums_bytes + counts_bytes);
  unsigned* nvalid = (unsigned*)(loss_sum + 1);

  hipMemsetAsync(sums, 0, sums_bytes + counts_bytes + 2 * sizeof(unsigned),
                 stream);

  const int pix_per_block = 4096;
  seg_count_kernel<<<npix_total / pix_per_block, 256, 0, stream>>>(
      labels, indexes, seg, counts, pix_per_block);

  segsum_mfma_kernel<<<B * cpi, 256, 0, stream>>>(feat, seg, sums, cpi);

  pairloss_kernel<<<B * NC, 256, 0, stream>>>(sums, counts, loss_sum, nvalid,
                                              D);
  finalize_kernel<<<1, 64, 0, stream>>>(loss_sum, nvalid, (float*)d_out, B);
}

// Round 13
// 317.743 us; speedup vs baseline: 1.6495x; 1.0586x over previous
//
#include <hip/hip_runtime.h>
#include <stdint.h>

#define NC 5
#define SEGS 160            // remapped: label*32 + (idx-1), idx in [1,32]
#define MT 5                // 5 M-tiles of 32
#define HW_ (512 * 512)
#define IGNORE_L 255
#define SENT 0xFF
#define KCHUNK 2048         // pixels per segsum block
#define SUP_PX 128          // superstep pixels (lane-pair covers 512 B/row)
#define NSUP (KCHUNK / SUP_PX)  // 16
#define TILE (SEGS * 128)

typedef __attribute__((ext_vector_type(8))) short short8v;
typedef __attribute__((ext_vector_type(16))) float f32x16;
typedef __attribute__((ext_vector_type(2))) unsigned short u16x2;
typedef __attribute__((ext_vector_type(2))) float float2v;
typedef __attribute__((ext_vector_type(2))) __bf16 bf16x2;
typedef __attribute__((ext_vector_type(2))) unsigned long long u64x2;

// ---------------- Pass 1: remapped seg ids + counts ----------------
__global__ __launch_bounds__(256) void seg_count_kernel(
    const int* __restrict__ labels, const int* __restrict__ indexes,
    uint8_t* __restrict__ seg, unsigned* __restrict__ counts,
    int pix_per_block) {
  __shared__ unsigned hist[SEGS + 1];
  for (int i = threadIdx.x; i < SEGS + 1; i += blockDim.x) hist[i] = 0u;
  __syncthreads();

  const long long base = (long long)blockIdx.x * pix_per_block;
  const int b = (int)(base / HW_);
  const int nvec = pix_per_block / 4;
  const int4* lab4 = (const int4*)(labels + base);
  const int4* idx4 = (const int4*)(indexes + base);
  uchar4* seg4 = (uchar4*)(seg + base);

  for (int k = threadIdx.x; k < nvec; k += blockDim.x) {
    int4 l = lab4[k];
    int4 ix = idx4[k];
    int s0 = (l.x == IGNORE_L) ? SEGS : l.x * 32 + ix.x - 1;
    int s1 = (l.y == IGNORE_L) ? SEGS : l.y * 32 + ix.y - 1;
    int s2 = (l.z == IGNORE_L) ? SEGS : l.z * 32 + ix.z - 1;
    int s3 = (l.w == IGNORE_L) ? SEGS : l.w * 32 + ix.w - 1;
    uchar4 sv;
    sv.x = (unsigned char)(s0 == SEGS ? SENT : s0);
    sv.y = (unsigned char)(s1 == SEGS ? SENT : s1);
    sv.z = (unsigned char)(s2 == SEGS ? SENT : s2);
    sv.w = (unsigned char)(s3 == SEGS ? SENT : s3);
    seg4[k] = sv;
    atomicAdd(&hist[s0], 1u);
    atomicAdd(&hist[s1], 1u);
    atomicAdd(&hist[s2], 1u);
    atomicAdd(&hist[s3], 1u);
  }
  __syncthreads();
  for (int i = threadIdx.x; i < SEGS; i += blockDim.x)
    if (hist[i]) atomicAdd(&counts[b * SEGS + i], hist[i]);
}

// ---------------- Pass 2: segment sums via one-hot MFMA GEMM ----------------
// R9 champion structure (2-deep 16-float4 register pipeline, 256 B/lane runs,
// LDS-staged seg bytes, atomic epilogue, 2 waves/SIMD) + v_perm seg
// expansion, inline one-hot targets, s_setprio around compute clusters.
struct SS {
  float4 f[16];   // 64 px of this lane's channel (256 B contiguous)
};

__global__ __launch_bounds__(256, 2) void segsum_mfma_kernel(
    const float* __restrict__ feat, const uint8_t* __restrict__ seg,
    float* __restrict__ sums, int chunks_per_img) {
  __shared__ unsigned long long sseg8[KCHUNK / 8];
  const int b = blockIdx.x / chunks_per_img;
  const int chunk = blockIdx.x % chunks_per_img;
  const int pbase = chunk * KCHUNK;

  const unsigned long long* gseg8 =
      (const unsigned long long*)(seg + (size_t)b * HW_ + pbase);
  sseg8[threadIdx.x] = gseg8[threadIdx.x];
  __syncthreads();

  const int l = threadIdx.x & 63;
  const int w = threadIdx.x >> 6;
  const int lane31 = l & 31;
  const int hi = l >> 5;
  const int ch = w * 32 + lane31;
  const unsigned lane2 = (unsigned)lane31 | ((unsigned)lane31 << 16);

  // lane's channel-row base; hi-half owns px [s*128+hi*64, +64)
  const float4* fp4 =
      (const float4*)(feat + ((size_t)b * 128 + ch) * HW_ + pbase) + hi * 16;
  const uint8_t* sp = (const uint8_t*)sseg8 + hi * 64;

  f32x16 acc[MT];
  #pragma unroll
  for (int m = 0; m < MT; ++m) acc[m] = (f32x16)(0.f);

  #define LOAD_SS(dst, s)                                             \
    do {                                                              \
      _Pragma("unroll") for (int i = 0; i < 16; ++i)                  \
          (dst).f[i] = fp4[(size_t)(s)*32 + i];                       \
    } while (0)

  #define KSTEP(f0, f1, sb)                                           \
    do {                                                              \
      unsigned slo = (unsigned)(sb);                                  \
      unsigned shi = (unsigned)((sb) >> 32);                          \
      unsigned svp[4];                                                \
      svp[0] = __builtin_amdgcn_perm(0u, slo, 0x0C010C00u) ^ lane2;   \
      svp[1] = __builtin_amdgcn_perm(0u, slo, 0x0C030C02u) ^ lane2;   \
      svp[2] = __builtin_amdgcn_perm(0u, shi, 0x0C010C00u) ^ lane2;   \
      svp[3] = __builtin_amdgcn_perm(0u, shi, 0x0C030C02u) ^ lane2;   \
      float fs[8] = {(f0).x, (f0).y, (f0).z, (f0).w,                  \
                     (f1).x, (f1).y, (f1).z, (f1).w};                 \
      union { unsigned u[4]; short8v v; } bhi, blo;                   \
      _Pragma("unroll") for (int j = 0; j < 4; ++j) {                 \
        float2v f2 = {fs[2 * j], fs[2 * j + 1]};                      \
        bf16x2 h2 = __builtin_convertvector(f2, bf16x2);              \
        unsigned hb = __builtin_bit_cast(unsigned, h2);               \
        bhi.u[j] = hb;                                                \
        float fh0 = __builtin_bit_cast(float, hb << 16);              \
        float fh1 = __builtin_bit_cast(float, hb & 0xFFFF0000u);      \
        float2v l2 = {f2.x - fh0, f2.y - fh1};                        \
        bf16x2 lo2 = __builtin_convertvector(l2, bf16x2);             \
        blo.u[j] = __builtin_bit_cast(unsigned, lo2);                 \
      }                                                               \
      _Pragma("unroll") for (int m = 0; m < MT; ++m) {                \
        const unsigned m2 = (unsigned)(m * 32) * 0x10001u;            \
        union { unsigned u[4]; short8v v; } a;                        \
        _Pragma("unroll") for (int j = 0; j < 4; ++j) {               \
          u16x2 y = __builtin_bit_cast(u16x2, svp[j] ^ m2);           \
          u16x2 nz = __builtin_elementwise_min(y, (u16x2)(unsigned short)1); \
          u16x2 msk = nz - (u16x2)(unsigned short)1;                  \
          u16x2 av = msk & (u16x2)(unsigned short)0x3F80;             \
          a.u[j] = __builtin_bit_cast(unsigned, av);                  \
        }                                                             \
        acc[m] = __builtin_amdgcn_mfma_f32_32x32x16_bf16(a.v, bhi.v,  \
                                                         acc[m], 0, 0, 0); \
        acc[m] = __builtin_amdgcn_mfma_f32_32x32x16_bf16(a.v, blo.v,  \
                                                         acc[m], 0, 0, 0); \
      }                                                               \
    } while (0)

  // 8 ksteps per superstep; compute cluster runs at raised wave priority
  #define COMPUTE_SS(src, s)                                          \
    do {                                                              \
      u64x2 g0 = *(const u64x2*)(sp + (size_t)(s)*128);               \
      u64x2 g1 = *(const u64x2*)(sp + (size_t)(s)*128 + 16);          \
      u64x2 g2 = *(const u64x2*)(sp + (size_t)(s)*128 + 32);          \
      u64x2 g3 = *(const u64x2*)(sp + (size_t)(s)*128 + 48);          \
      __builtin_amdgcn_s_setprio(1);                                  \
      KSTEP((src).f[0], (src).f[1], g0.x);                            \
      KSTEP((src).f[2], (src).f[3], g0.y);                            \
      KSTEP((src).f[4], (src).f[5], g1.x);                            \
      KSTEP((src).f[6], (src).f[7], g1.y);                            \
      KSTEP((src).f[8], (src).f[9], g2.x);                            \
      KSTEP((src).f[10], (src).f[11], g2.y);                          \
      KSTEP((src).f[12], (src).f[13], g3.x);                          \
      KSTEP((src).f[14], (src).f[15], g3.y);                          \
      __builtin_amdgcn_s_setprio(0);                                  \
    } while (0)

  SS bufA, bufB;
  LOAD_SS(bufA, 0);
  for (int s = 0; s < NSUP; s += 2) {
    LOAD_SS(bufB, s + 1);
    COMPUTE_SS(bufA, s);
    if (s + 2 < NSUP) LOAD_SS(bufA, s + 2);
    COMPUTE_SS(bufB, s + 1);
  }

  // epilogue: C/D layout col=lane&31, row=(r&3)+8*(r>>2)+4*hi
  #pragma unroll
  for (int m = 0; m < MT; ++m) {
    #pragma unroll
    for (int r = 0; r < 16; ++r) {
      int s = m * 32 + (r & 3) + 8 * (r >> 2) + 4 * hi;
      float v = acc[m][r];
      if (v != 0.f)
        atomicAdd(&sums[((size_t)b * SEGS + s) * 128 + ch], v);
    }
  }
}

// ---------------- Pass 3: per-(image,class) pairwise loss ----------------
__global__ __launch_bounds__(256) void pairloss_kernel(
    const float* __restrict__ sums, const unsigned* __restrict__ counts,
    float* __restrict__ loss_sum, unsigned* __restrict__ nvalid, int D) {
  const int b = blockIdx.x / NC;
  const int c = blockIdx.x % NC;

  __shared__ float sh_mean[32 * 128];
  __shared__ float sh_cnt[33];
  __shared__ int list[33];
  __shared__ int Ksh;
  __shared__ uchar2 pairs[32 * 31 / 2];
  __shared__ double wred[4];

  if (threadIdx.x == 0) {
    int K = 0;
    for (int ii = 0; ii < 32; ++ii) {
      unsigned cnt = counts[b * SEGS + c * 32 + ii];
      if (cnt >= 2u) {
        list[K] = ii;
        sh_cnt[K] = (float)cnt;
        ++K;
      }
    }
    Ksh = K;
    int p = 0;
    for (int i = 0; i < K; ++i)
      for (int j = i + 1; j < K; ++j) {
        pairs[p].x = (unsigned char)i;
        pairs[p].y = (unsigned char)j;
        ++p;
      }
  }
  __syncthreads();
  const int K = Ksh;
  if (K == 0) return;

  for (int idx = threadIdx.x; idx < K * D; idx += blockDim.x) {
    int k = idx / 128, d = idx % 128;
    int s = c * 32 + list[k];
    sh_mean[k * 128 + d] = sums[((size_t)b * SEGS + s) * D + d] / sh_cnt[k];
  }
  __syncthreads();

  const int npairs = K * (K - 1) / 2;
  const int total = npairs * 128;
  float local = 0.f;
  for (int idx = threadIdx.x; idx < total; idx += blockDim.x) {
    int p = idx >> 7, d = idx & 127;
    int i = pairs[p].x, j = pairs[p].y;
    local += fabsf(sh_mean[i * 128 + d] - sh_mean[j * 128 + d]);
  }

  double v = (double)local;
  #pragma unroll
  for (int off = 32; off; off >>= 1) v += __shfl_down(v, off, 64);
  const int wave = threadIdx.x >> 6;
  if ((threadIdx.x & 63) == 0) wred[wave] = v;
  __syncthreads();
  if (threadIdx.x == 0) {
    double ssum = 2.0 * (wred[0] + wred[1] + wred[2] + wred[3]);
    double ret = ssum / ((double)K * (double)K * (double)D);
    double loss = (ret < 1.0) ? 0.5 * ret * ret : ret - 0.5;
    atomicAdd(loss_sum, (float)loss);
    atomicAdd(nvalid, 1u);
  }
}

// ---------------- Pass 4: finalize ----------------
__global__ void finalize_kernel(const float* __restrict__ loss_sum,
                                const unsigned* __restrict__ nvalid,
                                float* __restrict__ out, int B) {
  if (threadIdx.x == 0) {
    unsigned n = *nvalid;
    out[0] = n ? (*loss_sum / (float)n) / (float)B : 0.f;
  }
}

extern "C" void kernel_launch(void* const* d_in, const int* in_sizes, int n_in,
                              void* d_out, int out_size, void* d_ws,
                              size_t ws_size, hipStream_t stream) {
  const float* feat = (const float*)d_in[0];
  const int* labels = (const int*)d_in[1];
  const int* indexes = (const int*)d_in[2];

  const int npix_total = in_sizes[1];          // B*H*W
  const int B = npix_total / HW_;              // 8
  const int D = in_sizes[0] / npix_total;      // 128
  const int cpi = HW_ / KCHUNK;                // 128 chunks per image

  uint8_t* seg = (uint8_t*)d_ws;
  size_t off = ((size_t)npix_total + 255) & ~(size_t)255;
  float* sums = (float*)((char*)d_ws + off);
  size_t sums_bytes = (size_t)B * TILE * sizeof(float);
  unsigned* counts = (unsigned*)((char*)d_ws + off + sums_bytes);
  size_t counts_bytes = (size_t)B * SEGS * sizeof(unsigned);
  float* loss_sum = (float*)((char*)d_ws + off + sums_bytes + counts_bytes);
  unsigned* nvalid = (unsigned*)(loss_sum + 1);

  hipMemsetAsync(sums, 0, sums_bytes + counts_bytes + 2 * sizeof(unsigned),
                 stream);

  const int pix_per_block = 4096;
  seg_count_kernel<<<npix_total / pix_per_block, 256, 0, stream>>>(
      labels, indexes, seg, counts, pix_per_block);

  segsum_mfma_kernel<<<B * cpi, 256, 0, stream>>>(feat, seg, sums, cpi);

  pairloss_kernel<<<B * NC, 256, 0, stream>>>(sums, counts, loss_sum, nvalid,
                                              D);
  finalize_kernel<<<1, 64, 0, stream>>>(loss_sum, nvalid, (float*)d_out, B);
}